// Round 17
// baseline (170.595 us; speedup 1.0000x reference)
//
#include <hip/hip_runtime.h>
#include <stdint.h>

// VectorQuantizer: z [32768,64], codebook [1024,64] (dtype sniffed bf16/f32).
// d_out FLOAT32: z_q_st [2097152] ++ loss [1] ++ indices [32768].
// Bit-exact replication of the reference f32 arithmetic (numpy pairwise sums,
// sequential non-fused dot, f32 final adds, first-index argmin).
//
// R20 = R16 (137.3us verified best) + ONE change: inner-loop math packed as
// v2f (<2 x float>) so the backend emits v_pk_mul_f32/v_pk_add_f32 (CDNA
// packed f32: 2 independent RNE ops/inst) -> inner VALU issue count halves
// (128 -> 64 inst per d). Contraction into pk_fma (single rounding, WRONG)
// is blocked by '#pragma clang fp contract(off)' + separate mul/add exprs.
// Each packed half is the identical scalar RNE mul-then-add ascending-d
// chain -> bit-exact. R9/R11/R19 proved the compiler won't deepen load
// batching; R18 proved TLP is capped (grid == CU count) -- issue count is
// the remaining lever. Everything else byte-identical to R16.
#define N_ROWS 32768
#define DIM 64
#define K_CODES 1024
#define ROWS_PER_BLOCK 128
#define THREADS 512
#define CHUNK 256
#define NCHUNK (K_CODES / CHUNK)              // 4
#define NBLOCKS (N_ROWS / ROWS_PER_BLOCK)     // 256
#define N_ELEMS (N_ROWS * DIM)                // 2097152
#define ZT_STRIDE 128
#define CT_STRIDE 256

typedef float v2f __attribute__((ext_vector_type(2)));

// workspace layout (bytes):
// [4096,4100)   uint counter (memset to 0 per launch)
// [8192,10240)  double partials[NBLOCKS=256]

__device__ __forceinline__ float bfbits(uint32_t b) { return __uint_as_float(b << 16); }
__device__ __forceinline__ float bf_lo(uint32_t u) { return __uint_as_float(u << 16); }
__device__ __forceinline__ float bf_hi(uint32_t u) { return __uint_as_float(u & 0xFFFF0000u); }

// round f32 -> nearest bf16 value, returned AS f32 (RNE; finite inputs).
__device__ __forceinline__ float round_bf16(float f) {
  uint32_t u = __float_as_uint(f);
  uint32_t r = ((u + 0x7FFFu + ((u >> 16) & 1u)) >> 16) << 16;
  return __uint_as_float(r);
}

// zt split-plane column: row = 8*TR + s -> col = TR*4 + (s>>2)*64 + (s&3).
__device__ __forceinline__ int zcol(int row) {
  return ((row >> 3) << 2) + (((row >> 2) & 1) << 6) + (row & 3);
}

// numpy pairwise_sum for n=64 (8 accumulators, 8 rounds, numpy's combine tree).
template <typename F>
__device__ __forceinline__ float np_sum64(F get) {
  float r0 = get(0), r1 = get(1), r2 = get(2), r3 = get(3);
  float r4 = get(4), r5 = get(5), r6 = get(6), r7 = get(7);
  for (int i = 8; i < 64; i += 8) {
    r0 = __fadd_rn(r0, get(i + 0)); r1 = __fadd_rn(r1, get(i + 1));
    r2 = __fadd_rn(r2, get(i + 2)); r3 = __fadd_rn(r3, get(i + 3));
    r4 = __fadd_rn(r4, get(i + 4)); r5 = __fadd_rn(r5, get(i + 5));
    r6 = __fadd_rn(r6, get(i + 6)); r7 = __fadd_rn(r7, get(i + 7));
  }
  return __fadd_rn(__fadd_rn(__fadd_rn(r0, r1), __fadd_rn(r2, r3)),
                   __fadd_rn(__fadd_rn(r4, r5), __fadd_rn(r6, r7)));
}

// Thread tile: TR = tid&15 (8 rows), TK = tid>>4 in [0,32) (8 codes of 256).
__global__ __launch_bounds__(THREADS, 1) void vq_kernel(
    const void* __restrict__ z, const void* __restrict__ cb,
    float* __restrict__ out, double* __restrict__ partials,
    unsigned int* __restrict__ counter) {
#pragma clang fp contract(off)
  const int tid = threadIdx.x;

  __shared__ int s_cnt[2];
  __shared__ int s_last;
  __shared__ float zt[DIM][ZT_STRIDE];          // 32 KB, split-plane + XOR swz
  __shared__ float ct[DIM][CT_STRIDE];          // 64 KB, XOR swz
  __shared__ float s_cc[K_CODES];               // 4 KB
  __shared__ float s_zz[ROWS_PER_BLOCK];        // 512 B
  __shared__ float s_bestW[8][ROWS_PER_BLOCK];  // 4 KB
  __shared__ int   s_kW[8][ROWS_PER_BLOCK];     // 4 KB
  __shared__ int   s_win[ROWS_PER_BLOCK];       // 512 B
  __shared__ double s_loss[ROWS_PER_BLOCK];     // 1 KB

  // ---- per-block dtype sniff (identical logic/result in every block) ----
  if (tid < 2) s_cnt[tid] = 0;
  __syncthreads();
  if (tid < 128) {
    uint32_t wc = ((const uint32_t*)cb)[(size_t)tid * 255];
    float vc = fabsf(bfbits(wc & 0xFFFFu));
    if (vc == 0.0f || (vc > 5.9e-8f && vc < 32.0f)) atomicAdd(&s_cnt[1], 1);
    uint32_t wz = ((const uint32_t*)z)[(size_t)tid * 8191];
    float vz = fabsf(bfbits(wz & 0xFFFFu));
    if (vz == 0.0f || (vz > 5.9e-8f && vz < 32.0f)) atomicAdd(&s_cnt[0], 1);
  }
  __syncthreads();
  const bool z_bf16  = s_cnt[0] >= 96;
  const bool cb_bf16 = s_cnt[1] >= 96;

  const int TR = tid & 15;
  const int TK = tid >> 4;
  const size_t row0 = (size_t)blockIdx.x * ROWS_PER_BLOCK;

  // ---- s_cc from global: 2 codes/thread, 8-acc streaming numpy pairwise ----
  for (int kk = tid; kk < K_CODES; kk += THREADS) {
    float r0, r1, r2, r3, r4, r5, r6, r7;
    if (cb_bf16) {
      const uint4* cp = (const uint4*)((const uint16_t*)cb + (size_t)kk * DIM);
      uint4 u = cp[0];
      r0 = __fmul_rn(bf_lo(u.x), bf_lo(u.x)); r1 = __fmul_rn(bf_hi(u.x), bf_hi(u.x));
      r2 = __fmul_rn(bf_lo(u.y), bf_lo(u.y)); r3 = __fmul_rn(bf_hi(u.y), bf_hi(u.y));
      r4 = __fmul_rn(bf_lo(u.z), bf_lo(u.z)); r5 = __fmul_rn(bf_hi(u.z), bf_hi(u.z));
      r6 = __fmul_rn(bf_lo(u.w), bf_lo(u.w)); r7 = __fmul_rn(bf_hi(u.w), bf_hi(u.w));
      #pragma unroll
      for (int j = 1; j < 8; ++j) {
        u = cp[j];
        r0 = __fadd_rn(r0, __fmul_rn(bf_lo(u.x), bf_lo(u.x)));
        r1 = __fadd_rn(r1, __fmul_rn(bf_hi(u.x), bf_hi(u.x)));
        r2 = __fadd_rn(r2, __fmul_rn(bf_lo(u.y), bf_lo(u.y)));
        r3 = __fadd_rn(r3, __fmul_rn(bf_hi(u.y), bf_hi(u.y)));
        r4 = __fadd_rn(r4, __fmul_rn(bf_lo(u.z), bf_lo(u.z)));
        r5 = __fadd_rn(r5, __fmul_rn(bf_hi(u.z), bf_hi(u.z)));
        r6 = __fadd_rn(r6, __fmul_rn(bf_lo(u.w), bf_lo(u.w)));
        r7 = __fadd_rn(r7, __fmul_rn(bf_hi(u.w), bf_hi(u.w)));
      }
    } else {
      const float4* cp = (const float4*)((const float*)cb + (size_t)kk * DIM);
      float4 a = cp[0], b = cp[1];
      r0 = __fmul_rn(a.x, a.x); r1 = __fmul_rn(a.y, a.y);
      r2 = __fmul_rn(a.z, a.z); r3 = __fmul_rn(a.w, a.w);
      r4 = __fmul_rn(b.x, b.x); r5 = __fmul_rn(b.y, b.y);
      r6 = __fmul_rn(b.z, b.z); r7 = __fmul_rn(b.w, b.w);
      #pragma unroll
      for (int j = 1; j < 8; ++j) {
        a = cp[2 * j]; b = cp[2 * j + 1];
        r0 = __fadd_rn(r0, __fmul_rn(a.x, a.x));
        r1 = __fadd_rn(r1, __fmul_rn(a.y, a.y));
        r2 = __fadd_rn(r2, __fmul_rn(a.z, a.z));
        r3 = __fadd_rn(r3, __fmul_rn(a.w, a.w));
        r4 = __fadd_rn(r4, __fmul_rn(b.x, b.x));
        r5 = __fadd_rn(r5, __fmul_rn(b.y, b.y));
        r6 = __fadd_rn(r6, __fmul_rn(b.z, b.z));
        r7 = __fadd_rn(r7, __fmul_rn(b.w, b.w));
      }
    }
    s_cc[kk] = __fadd_rn(__fadd_rn(__fadd_rn(r0, r1), __fadd_rn(r2, r3)),
                         __fadd_rn(__fadd_rn(r4, r5), __fadd_rn(r6, r7)));
  }

  // ---- stage z transposed, split-plane + XOR swizzle (placement only) ----
  if (z_bf16) {
    const uint4* src = (const uint4*)((const uint16_t*)z + row0 * DIM);
    #pragma unroll
    for (int j = 0; j < 2; ++j) {
      int idx = tid + THREADS * j;              // [0,1024)
      int row = idx >> 3, w = idx & 7, d0 = w * 8;
      int col = zcol(row) ^ (w << 2);           // (d>>3)&7 == w for all 8 d's
      uint4 u = src[idx];
      zt[d0 + 0][col] = bf_lo(u.x); zt[d0 + 1][col] = bf_hi(u.x);
      zt[d0 + 2][col] = bf_lo(u.y); zt[d0 + 3][col] = bf_hi(u.y);
      zt[d0 + 4][col] = bf_lo(u.z); zt[d0 + 5][col] = bf_hi(u.z);
      zt[d0 + 6][col] = bf_lo(u.w); zt[d0 + 7][col] = bf_hi(u.w);
    }
  } else {
    const float4* src = (const float4*)((const float*)z + row0 * DIM);
    #pragma unroll
    for (int j = 0; j < 4; ++j) {
      int idx = tid + THREADS * j;              // [0,2048)
      int row = idx >> 4, d0 = (idx & 15) * 4;
      int col = zcol(row) ^ (((d0 >> 3) & 7) << 2);  // (d>>3) const over 4 d's
      float4 v = src[idx];
      zt[d0 + 0][col] = v.x; zt[d0 + 1][col] = v.y;
      zt[d0 + 2][col] = v.z; zt[d0 + 3][col] = v.w;
    }
  }
  __syncthreads();

  // zz per row = np.sum(z*z) in f32, numpy pairwise order over products.
  if (tid < ROWS_PER_BLOCK) {
    const int c0 = zcol(tid);
    s_zz[tid] = np_sum64([&](int d) {
      float v = zt[d][c0 ^ (((d >> 3) & 7) << 2)];
      return __fmul_rn(v, v); });
  }

  float best[8] = {3.4e38f, 3.4e38f, 3.4e38f, 3.4e38f,
                   3.4e38f, 3.4e38f, 3.4e38f, 3.4e38f};
  int bk[8] = {0, 0, 0, 0, 0, 0, 0, 0};
  // acc pairs over ki: acc2[ri][kp] covers codes {2kp, 2kp+1}.
  v2f acc2[8][4];
  #pragma unroll
  for (int ri = 0; ri < 8; ++ri)
    #pragma unroll
    for (int kp = 0; kp < 4; ++kp) acc2[ri][kp] = (v2f)(0.0f);

  for (int c = 0; c < NCHUNK; ++c) {
    __syncthreads();  // prev chunk compute done (c=0: zz done)
    // stage chunk c transposed + XOR swizzle (placement only)
    if (cb_bf16) {
      const uint4* src = (const uint4*)((const uint16_t*)cb + (size_t)c * CHUNK * DIM);
      #pragma unroll
      for (int j = 0; j < 4; ++j) {
        int idx = tid + THREADS * j;            // [0,2048)
        int kc = idx >> 3, w = idx & 7, d0 = w * 8;
        int col = kc ^ ((w & 3) << 3);          // (d>>3)&3 == w&3 for all 8 d's
        uint4 u = src[idx];
        ct[d0 + 0][col] = bf_lo(u.x); ct[d0 + 1][col] = bf_hi(u.x);
        ct[d0 + 2][col] = bf_lo(u.y); ct[d0 + 3][col] = bf_hi(u.y);
        ct[d0 + 4][col] = bf_lo(u.z); ct[d0 + 5][col] = bf_hi(u.z);
        ct[d0 + 6][col] = bf_lo(u.w); ct[d0 + 7][col] = bf_hi(u.w);
      }
    } else {
      const float4* src = (const float4*)((const float*)cb + (size_t)c * CHUNK * DIM);
      #pragma unroll
      for (int j = 0; j < 8; ++j) {
        int idx = tid + THREADS * j;            // [0,4096)
        int kc = idx >> 4, d0 = (idx & 15) * 4;
        int col = kc ^ (((d0 >> 3) & 3) << 3);
        float4 v = src[idx];
        ct[d0 + 0][col] = v.x; ct[d0 + 1][col] = v.y;
        ct[d0 + 2][col] = v.z; ct[d0 + 3][col] = v.w;
      }
    }
    __syncthreads();

    // inner: per d, 4 ds_read_b128 feed 64 packed VALU inst (v_pk_mul_f32 +
    // v_pk_add_f32; contract(off) forbids pk_fma fusion). Each packed half
    // is the scalar RNE mul-then-add chain ascending d == reference order.
    #pragma unroll 4
    for (int d = 0; d < DIM; ++d) {
      const int zs = ((d >> 3) & 7) << 2;
      const int cs = ((d >> 3) & 3) << 3;
      float4 zA = *(const float4*)&zt[d][(TR << 2) ^ zs];        // rows 8TR+0..3
      float4 zB = *(const float4*)&zt[d][((TR << 2) ^ zs) + 64]; // rows 8TR+4..7
      float4 cA = *(const float4*)&ct[d][(TK << 3) ^ cs];
      float4 cB = *(const float4*)&ct[d][((TK << 3) ^ cs) + 4];
      float zv[8] = {zA.x, zA.y, zA.z, zA.w, zB.x, zB.y, zB.z, zB.w};
      v2f cp2[4];
      cp2[0][0] = cA.x; cp2[0][1] = cA.y;
      cp2[1][0] = cA.z; cp2[1][1] = cA.w;
      cp2[2][0] = cB.x; cp2[2][1] = cB.y;
      cp2[3][0] = cB.z; cp2[3][1] = cB.w;
      #pragma unroll
      for (int ri = 0; ri < 8; ++ri) {
        v2f zr;
        zr[0] = zv[ri]; zr[1] = zv[ri];
        #pragma unroll
        for (int kp = 0; kp < 4; ++kp) {
          v2f m = zr * cp2[kp];                 // v_pk_mul_f32 (RNE per half)
          acc2[ri][kp] = acc2[ri][kp] + m;      // v_pk_add_f32 (RNE per half)
        }
      }
    }

    // epilogue: d2 = fl(fl(zz+cc) - fl(2*g)); per-thread k ascending, strict <.
    #pragma unroll
    for (int ri = 0; ri < 8; ++ri) {
      const float zzr = s_zz[TR * 8 + ri];
      #pragma unroll
      for (int ki = 0; ki < 8; ++ki) {
        const int k = c * CHUNK + TK * 8 + ki;
        float g = acc2[ri][ki >> 1][ki & 1];    // compile-time indices
        float e = __fsub_rn(__fadd_rn(zzr, s_cc[k]), __fmul_rn(2.0f, g));
        if (e < best[ri]) { best[ri] = e; bk[ri] = k; }
      }
      #pragma unroll
      for (int kp = 0; kp < 4; ++kp) acc2[ri][kp] = (v2f)(0.0f);
    }
  }

  // wave-level lexicographic merge across the 4 TK values in this wave.
  // Lex (d2,k) min is assoc/comm -> any merge order == first-index argmin.
  #pragma unroll
  for (int ri = 0; ri < 8; ++ri) {
    float v = best[ri]; int k = bk[ri];
    {
      float v2 = __shfl_xor(v, 16, 64); int k2 = __shfl_xor(k, 16, 64);
      if (v2 < v || (v2 == v && k2 < k)) { v = v2; k = k2; }
      v2 = __shfl_xor(v, 32, 64); k2 = __shfl_xor(k, 32, 64);
      if (v2 < v || (v2 == v && k2 < k)) { v = v2; k = k2; }
    }
    best[ri] = v; bk[ri] = k;
  }
  {
    const int lane = tid & 63, wv = tid >> 6;
    if (lane < 16) {
      #pragma unroll
      for (int ri = 0; ri < 8; ++ri) {
        s_bestW[wv][lane * 8 + ri] = best[ri];   // lane == TR here
        s_kW[wv][lane * 8 + ri] = bk[ri];
      }
    }
  }
  __syncthreads();

  if (tid < ROWS_PER_BLOCK) {
    // final lex merge across the 8 waves
    float b = 3.4e38f;
    int bbk = 0x7FFFFFFF;
    #pragma unroll
    for (int p = 0; p < 8; ++p) {
      float v = s_bestW[p][tid];
      int vk = s_kW[p][tid];
      if (v < b || (v == b && vk < bbk)) { b = v; bbk = vk; }
    }
    s_win[tid] = bbk;
    // Exact squared distance of the winner (fp64); exact z from zt column.
    const int c0 = zcol(tid);
    double acc2d = 0.0;
    if (cb_bf16) {
      const uint16_t* cp = (const uint16_t*)cb + (size_t)bbk * DIM;
      for (int d = 0; d < DIM; ++d) {
        double df = (double)zt[d][c0 ^ (((d >> 3) & 7) << 2)]
                  - (double)bfbits((uint32_t)cp[d]);
        acc2d = fma(df, df, acc2d);
      }
    } else {
      const float* cp = (const float*)cb + (size_t)bbk * DIM;
      for (int d = 0; d < DIM; ++d) {
        double df = (double)zt[d][c0 ^ (((d >> 3) & 7) << 2)] - (double)cp[d];
        acc2d = fma(df, df, acc2d);
      }
    }
    s_loss[tid] = acc2d;
    out[(size_t)N_ELEMS + 1 + row0 + tid] = round_bf16((float)bbk);
  }
  __syncthreads();

  // z_q write: 128 rows x 64 dims = 8192 floats, 512 threads x 16, coalesced.
  const size_t base = row0 * DIM;
  #pragma unroll
  for (int j = 0; j < 16; ++j) {
    int idx = tid + THREADS * j;
    int rr = idx >> 6, dd = idx & 63;
    int w = s_win[rr];
    float v;
    if (cb_bf16) v = bfbits((uint32_t)((const uint16_t*)cb)[(size_t)w * DIM + dd]);
    else         v = round_bf16(((const float*)cb)[(size_t)w * DIM + dd]);
    out[base + idx] = v;
  }

  // ---- per-block loss partial + last-block final reduction ----
  if (tid == 0) {
    double s = 0.0;
    for (int i = 0; i < ROWS_PER_BLOCK; ++i) s += s_loss[i];
    partials[blockIdx.x] = s;
    __threadfence();                       // release partials (device scope)
    unsigned int old = atomicAdd(counter, 1u);
    s_last = (old == NBLOCKS - 1) ? 1 : 0;
  }
  __syncthreads();
  if (s_last) {
    __threadfence();                       // acquire all partials
    if (tid < 128) s_loss[tid] = partials[tid] + partials[tid + 128];
    __syncthreads();
    if (tid == 0) {
      double t = 0.0;
      for (int i = 0; i < 128; ++i) t += s_loss[i];
      out[N_ELEMS] = round_bf16((float)(1.25 * t / (double)N_ELEMS));
    }
  }
}

extern "C" void kernel_launch(void* const* d_in, const int* in_sizes, int n_in,
                              void* d_out, int out_size, void* d_ws, size_t ws_size,
                              hipStream_t stream) {
  const void* z  = d_in[0];
  const void* cb = d_in[1];
  float* out = (float*)d_out;
  uint8_t* ws = (uint8_t*)d_ws;
  unsigned int* counter = (unsigned int*)(ws + 4096);
  double* partials = (double*)(ws + 8192);

  hipMemsetAsync(counter, 0, 4, stream);
  vq_kernel<<<NBLOCKS, THREADS, 0, stream>>>(z, cb, out, partials, counter);
}

// Round 18
// 134.032 us; speedup vs baseline: 1.2728x; 1.2728x over previous
//
#include <hip/hip_runtime.h>
#include <stdint.h>

// VectorQuantizer: z [32768,64], codebook [1024,64] (dtype sniffed bf16/f32).
// d_out FLOAT32: z_q_st [2097152] ++ loss [1] ++ indices [32768].
// Bit-exact replication of the reference f32 arithmetic (numpy pairwise sums,
// sequential non-fused dot, f32 final adds, first-index argmin).
//
// R21 = R16 (137.3us verified best) + ONE change: modulo last-block counter
// ((old+1) % NBLOCKS == 0 -- correct for ANY initial value, so no reset
// needed) replaces hipMemsetAsync+reset counter -> 1 dispatch total.
// Falsified-levers ledger (single-variable, counters-read): load-batching
// hints (R9/R11/R19: compiler re-rolls), 1024-thr TLP (R18: VGPR floor
// breaks 8x8 acc tile), coop-launch (R17), packed f32 (R20: scalarized,
// VALUBusy up + dur up). Residual vq gap (89us vs 55us VALU floor) is
// 2-wave-lockstep LDS-window serialization, structurally pinned.
#define N_ROWS 32768
#define DIM 64
#define K_CODES 1024
#define ROWS_PER_BLOCK 128
#define THREADS 512
#define CHUNK 256
#define NCHUNK (K_CODES / CHUNK)              // 4
#define NBLOCKS (N_ROWS / ROWS_PER_BLOCK)     // 256
#define N_ELEMS (N_ROWS * DIM)                // 2097152
#define ZT_STRIDE 128
#define CT_STRIDE 256

// workspace layout (bytes):
// [4096,4100)   uint counter (monotonic; modulo logic -> no reset required)
// [8192,10240)  double partials[NBLOCKS=256]

__device__ __forceinline__ float bfbits(uint32_t b) { return __uint_as_float(b << 16); }
__device__ __forceinline__ float bf_lo(uint32_t u) { return __uint_as_float(u << 16); }
__device__ __forceinline__ float bf_hi(uint32_t u) { return __uint_as_float(u & 0xFFFF0000u); }

// round f32 -> nearest bf16 value, returned AS f32 (RNE; finite inputs).
__device__ __forceinline__ float round_bf16(float f) {
  uint32_t u = __float_as_uint(f);
  uint32_t r = ((u + 0x7FFFu + ((u >> 16) & 1u)) >> 16) << 16;
  return __uint_as_float(r);
}

// zt split-plane column: row = 8*TR + s -> col = TR*4 + (s>>2)*64 + (s&3).
__device__ __forceinline__ int zcol(int row) {
  return ((row >> 3) << 2) + (((row >> 2) & 1) << 6) + (row & 3);
}

// numpy pairwise_sum for n=64 (8 accumulators, 8 rounds, numpy's combine tree).
template <typename F>
__device__ __forceinline__ float np_sum64(F get) {
  float r0 = get(0), r1 = get(1), r2 = get(2), r3 = get(3);
  float r4 = get(4), r5 = get(5), r6 = get(6), r7 = get(7);
  for (int i = 8; i < 64; i += 8) {
    r0 = __fadd_rn(r0, get(i + 0)); r1 = __fadd_rn(r1, get(i + 1));
    r2 = __fadd_rn(r2, get(i + 2)); r3 = __fadd_rn(r3, get(i + 3));
    r4 = __fadd_rn(r4, get(i + 4)); r5 = __fadd_rn(r5, get(i + 5));
    r6 = __fadd_rn(r6, get(i + 6)); r7 = __fadd_rn(r7, get(i + 7));
  }
  return __fadd_rn(__fadd_rn(__fadd_rn(r0, r1), __fadd_rn(r2, r3)),
                   __fadd_rn(__fadd_rn(r4, r5), __fadd_rn(r6, r7)));
}

// Thread tile: TR = tid&15 (8 rows), TK = tid>>4 in [0,32) (8 codes of 256).
__global__ __launch_bounds__(THREADS, 1) void vq_kernel(
    const void* __restrict__ z, const void* __restrict__ cb,
    float* __restrict__ out, double* __restrict__ partials,
    unsigned int* __restrict__ counter) {
  const int tid = threadIdx.x;

  __shared__ int s_cnt[2];
  __shared__ int s_last;
  __shared__ float zt[DIM][ZT_STRIDE];          // 32 KB, split-plane + XOR swz
  __shared__ float ct[DIM][CT_STRIDE];          // 64 KB, XOR swz
  __shared__ float s_cc[K_CODES];               // 4 KB
  __shared__ float s_zz[ROWS_PER_BLOCK];        // 512 B
  __shared__ float s_bestW[8][ROWS_PER_BLOCK];  // 4 KB
  __shared__ int   s_kW[8][ROWS_PER_BLOCK];     // 4 KB
  __shared__ int   s_win[ROWS_PER_BLOCK];       // 512 B
  __shared__ double s_loss[ROWS_PER_BLOCK];     // 1 KB

  // ---- per-block dtype sniff (identical logic/result in every block) ----
  if (tid < 2) s_cnt[tid] = 0;
  __syncthreads();
  if (tid < 128) {
    uint32_t wc = ((const uint32_t*)cb)[(size_t)tid * 255];
    float vc = fabsf(bfbits(wc & 0xFFFFu));
    if (vc == 0.0f || (vc > 5.9e-8f && vc < 32.0f)) atomicAdd(&s_cnt[1], 1);
    uint32_t wz = ((const uint32_t*)z)[(size_t)tid * 8191];
    float vz = fabsf(bfbits(wz & 0xFFFFu));
    if (vz == 0.0f || (vz > 5.9e-8f && vz < 32.0f)) atomicAdd(&s_cnt[0], 1);
  }
  __syncthreads();
  const bool z_bf16  = s_cnt[0] >= 96;
  const bool cb_bf16 = s_cnt[1] >= 96;

  const int TR = tid & 15;
  const int TK = tid >> 4;
  const size_t row0 = (size_t)blockIdx.x * ROWS_PER_BLOCK;

  // ---- s_cc from global: 2 codes/thread, 8-acc streaming numpy pairwise ----
  for (int kk = tid; kk < K_CODES; kk += THREADS) {
    float r0, r1, r2, r3, r4, r5, r6, r7;
    if (cb_bf16) {
      const uint4* cp = (const uint4*)((const uint16_t*)cb + (size_t)kk * DIM);
      uint4 u = cp[0];
      r0 = __fmul_rn(bf_lo(u.x), bf_lo(u.x)); r1 = __fmul_rn(bf_hi(u.x), bf_hi(u.x));
      r2 = __fmul_rn(bf_lo(u.y), bf_lo(u.y)); r3 = __fmul_rn(bf_hi(u.y), bf_hi(u.y));
      r4 = __fmul_rn(bf_lo(u.z), bf_lo(u.z)); r5 = __fmul_rn(bf_hi(u.z), bf_hi(u.z));
      r6 = __fmul_rn(bf_lo(u.w), bf_lo(u.w)); r7 = __fmul_rn(bf_hi(u.w), bf_hi(u.w));
      #pragma unroll
      for (int j = 1; j < 8; ++j) {
        u = cp[j];
        r0 = __fadd_rn(r0, __fmul_rn(bf_lo(u.x), bf_lo(u.x)));
        r1 = __fadd_rn(r1, __fmul_rn(bf_hi(u.x), bf_hi(u.x)));
        r2 = __fadd_rn(r2, __fmul_rn(bf_lo(u.y), bf_lo(u.y)));
        r3 = __fadd_rn(r3, __fmul_rn(bf_hi(u.y), bf_hi(u.y)));
        r4 = __fadd_rn(r4, __fmul_rn(bf_lo(u.z), bf_lo(u.z)));
        r5 = __fadd_rn(r5, __fmul_rn(bf_hi(u.z), bf_hi(u.z)));
        r6 = __fadd_rn(r6, __fmul_rn(bf_lo(u.w), bf_lo(u.w)));
        r7 = __fadd_rn(r7, __fmul_rn(bf_hi(u.w), bf_hi(u.w)));
      }
    } else {
      const float4* cp = (const float4*)((const float*)cb + (size_t)kk * DIM);
      float4 a = cp[0], b = cp[1];
      r0 = __fmul_rn(a.x, a.x); r1 = __fmul_rn(a.y, a.y);
      r2 = __fmul_rn(a.z, a.z); r3 = __fmul_rn(a.w, a.w);
      r4 = __fmul_rn(b.x, b.x); r5 = __fmul_rn(b.y, b.y);
      r6 = __fmul_rn(b.z, b.z); r7 = __fmul_rn(b.w, b.w);
      #pragma unroll
      for (int j = 1; j < 8; ++j) {
        a = cp[2 * j]; b = cp[2 * j + 1];
        r0 = __fadd_rn(r0, __fmul_rn(a.x, a.x));
        r1 = __fadd_rn(r1, __fmul_rn(a.y, a.y));
        r2 = __fadd_rn(r2, __fmul_rn(a.z, a.z));
        r3 = __fadd_rn(r3, __fmul_rn(a.w, a.w));
        r4 = __fadd_rn(r4, __fmul_rn(b.x, b.x));
        r5 = __fadd_rn(r5, __fmul_rn(b.y, b.y));
        r6 = __fadd_rn(r6, __fmul_rn(b.z, b.z));
        r7 = __fadd_rn(r7, __fmul_rn(b.w, b.w));
      }
    }
    s_cc[kk] = __fadd_rn(__fadd_rn(__fadd_rn(r0, r1), __fadd_rn(r2, r3)),
                         __fadd_rn(__fadd_rn(r4, r5), __fadd_rn(r6, r7)));
  }

  // ---- stage z transposed, split-plane + XOR swizzle (placement only) ----
  if (z_bf16) {
    const uint4* src = (const uint4*)((const uint16_t*)z + row0 * DIM);
    #pragma unroll
    for (int j = 0; j < 2; ++j) {
      int idx = tid + THREADS * j;              // [0,1024)
      int row = idx >> 3, w = idx & 7, d0 = w * 8;
      int col = zcol(row) ^ (w << 2);           // (d>>3)&7 == w for all 8 d's
      uint4 u = src[idx];
      zt[d0 + 0][col] = bf_lo(u.x); zt[d0 + 1][col] = bf_hi(u.x);
      zt[d0 + 2][col] = bf_lo(u.y); zt[d0 + 3][col] = bf_hi(u.y);
      zt[d0 + 4][col] = bf_lo(u.z); zt[d0 + 5][col] = bf_hi(u.z);
      zt[d0 + 6][col] = bf_lo(u.w); zt[d0 + 7][col] = bf_hi(u.w);
    }
  } else {
    const float4* src = (const float4*)((const float*)z + row0 * DIM);
    #pragma unroll
    for (int j = 0; j < 4; ++j) {
      int idx = tid + THREADS * j;              // [0,2048)
      int row = idx >> 4, d0 = (idx & 15) * 4;
      int col = zcol(row) ^ (((d0 >> 3) & 7) << 2);  // (d>>3) const over 4 d's
      float4 v = src[idx];
      zt[d0 + 0][col] = v.x; zt[d0 + 1][col] = v.y;
      zt[d0 + 2][col] = v.z; zt[d0 + 3][col] = v.w;
    }
  }
  __syncthreads();

  // zz per row = np.sum(z*z) in f32, numpy pairwise order over products.
  if (tid < ROWS_PER_BLOCK) {
    const int c0 = zcol(tid);
    s_zz[tid] = np_sum64([&](int d) {
      float v = zt[d][c0 ^ (((d >> 3) & 7) << 2)];
      return __fmul_rn(v, v); });
  }

  float best[8] = {3.4e38f, 3.4e38f, 3.4e38f, 3.4e38f,
                   3.4e38f, 3.4e38f, 3.4e38f, 3.4e38f};
  int bk[8] = {0, 0, 0, 0, 0, 0, 0, 0};
  float acc[8][8];
  #pragma unroll
  for (int ri = 0; ri < 8; ++ri)
    #pragma unroll
    for (int ki = 0; ki < 8; ++ki) acc[ri][ki] = 0.0f;

  for (int c = 0; c < NCHUNK; ++c) {
    __syncthreads();  // prev chunk compute done (c=0: zz done)
    // stage chunk c transposed + XOR swizzle (placement only)
    if (cb_bf16) {
      const uint4* src = (const uint4*)((const uint16_t*)cb + (size_t)c * CHUNK * DIM);
      #pragma unroll
      for (int j = 0; j < 4; ++j) {
        int idx = tid + THREADS * j;            // [0,2048)
        int kc = idx >> 3, w = idx & 7, d0 = w * 8;
        int col = kc ^ ((w & 3) << 3);          // (d>>3)&3 == w&3 for all 8 d's
        uint4 u = src[idx];
        ct[d0 + 0][col] = bf_lo(u.x); ct[d0 + 1][col] = bf_hi(u.x);
        ct[d0 + 2][col] = bf_lo(u.y); ct[d0 + 3][col] = bf_hi(u.y);
        ct[d0 + 4][col] = bf_lo(u.z); ct[d0 + 5][col] = bf_hi(u.z);
        ct[d0 + 6][col] = bf_lo(u.w); ct[d0 + 7][col] = bf_hi(u.w);
      }
    } else {
      const float4* src = (const float4*)((const float*)cb + (size_t)c * CHUNK * DIM);
      #pragma unroll
      for (int j = 0; j < 8; ++j) {
        int idx = tid + THREADS * j;            // [0,4096)
        int kc = idx >> 4, d0 = (idx & 15) * 4;
        int col = kc ^ (((d0 >> 3) & 3) << 3);
        float4 v = src[idx];
        ct[d0 + 0][col] = v.x; ct[d0 + 1][col] = v.y;
        ct[d0 + 2][col] = v.z; ct[d0 + 3][col] = v.w;
      }
    }
    __syncthreads();

    // inner: per d, 4 ds_read_b128 feed 128 VALU ops (non-fused; per
    // (row,code) chain is ascending d == reference einsum order).
    #pragma unroll 4
    for (int d = 0; d < DIM; ++d) {
      const int zs = ((d >> 3) & 7) << 2;
      const int cs = ((d >> 3) & 3) << 3;
      float4 zA = *(const float4*)&zt[d][(TR << 2) ^ zs];        // rows 8TR+0..3
      float4 zB = *(const float4*)&zt[d][((TR << 2) ^ zs) + 64]; // rows 8TR+4..7
      float4 cA = *(const float4*)&ct[d][(TK << 3) ^ cs];
      float4 cB = *(const float4*)&ct[d][((TK << 3) ^ cs) + 4];
      float zv[8] = {zA.x, zA.y, zA.z, zA.w, zB.x, zB.y, zB.z, zB.w};
      float cv[8] = {cA.x, cA.y, cA.z, cA.w, cB.x, cB.y, cB.z, cB.w};
      #pragma unroll
      for (int ri = 0; ri < 8; ++ri)
        #pragma unroll
        for (int ki = 0; ki < 8; ++ki)
          acc[ri][ki] = __fadd_rn(acc[ri][ki], __fmul_rn(zv[ri], cv[ki]));
    }

    // epilogue: d2 = fl(fl(zz+cc) - fl(2*g)); per-thread k ascending, strict <.
    #pragma unroll
    for (int ri = 0; ri < 8; ++ri) {
      const float zzr = s_zz[TR * 8 + ri];
      #pragma unroll
      for (int ki = 0; ki < 8; ++ki) {
        const int k = c * CHUNK + TK * 8 + ki;
        float e = __fsub_rn(__fadd_rn(zzr, s_cc[k]), __fmul_rn(2.0f, acc[ri][ki]));
        if (e < best[ri]) { best[ri] = e; bk[ri] = k; }
        acc[ri][ki] = 0.0f;
      }
    }
  }

  // wave-level lexicographic merge across the 4 TK values in this wave.
  // Lex (d2,k) min is assoc/comm -> any merge order == first-index argmin.
  #pragma unroll
  for (int ri = 0; ri < 8; ++ri) {
    float v = best[ri]; int k = bk[ri];
    {
      float v2 = __shfl_xor(v, 16, 64); int k2 = __shfl_xor(k, 16, 64);
      if (v2 < v || (v2 == v && k2 < k)) { v = v2; k = k2; }
      v2 = __shfl_xor(v, 32, 64); k2 = __shfl_xor(k, 32, 64);
      if (v2 < v || (v2 == v && k2 < k)) { v = v2; k = k2; }
    }
    best[ri] = v; bk[ri] = k;
  }
  {
    const int lane = tid & 63, wv = tid >> 6;
    if (lane < 16) {
      #pragma unroll
      for (int ri = 0; ri < 8; ++ri) {
        s_bestW[wv][lane * 8 + ri] = best[ri];   // lane == TR here
        s_kW[wv][lane * 8 + ri] = bk[ri];
      }
    }
  }
  __syncthreads();

  if (tid < ROWS_PER_BLOCK) {
    // final lex merge across the 8 waves
    float b = 3.4e38f;
    int bbk = 0x7FFFFFFF;
    #pragma unroll
    for (int p = 0; p < 8; ++p) {
      float v = s_bestW[p][tid];
      int vk = s_kW[p][tid];
      if (v < b || (v == b && vk < bbk)) { b = v; bbk = vk; }
    }
    s_win[tid] = bbk;
    // Exact squared distance of the winner (fp64); exact z from zt column.
    const int c0 = zcol(tid);
    double acc2 = 0.0;
    if (cb_bf16) {
      const uint16_t* cp = (const uint16_t*)cb + (size_t)bbk * DIM;
      for (int d = 0; d < DIM; ++d) {
        double df = (double)zt[d][c0 ^ (((d >> 3) & 7) << 2)]
                  - (double)bfbits((uint32_t)cp[d]);
        acc2 = fma(df, df, acc2);
      }
    } else {
      const float* cp = (const float*)cb + (size_t)bbk * DIM;
      for (int d = 0; d < DIM; ++d) {
        double df = (double)zt[d][c0 ^ (((d >> 3) & 7) << 2)] - (double)cp[d];
        acc2 = fma(df, df, acc2);
      }
    }
    s_loss[tid] = acc2;
    out[(size_t)N_ELEMS + 1 + row0 + tid] = round_bf16((float)bbk);
  }
  __syncthreads();

  // z_q write: 128 rows x 64 dims = 8192 floats, 512 threads x 16, coalesced.
  const size_t base = row0 * DIM;
  #pragma unroll
  for (int j = 0; j < 16; ++j) {
    int idx = tid + THREADS * j;
    int rr = idx >> 6, dd = idx & 63;
    int w = s_win[rr];
    float v;
    if (cb_bf16) v = bfbits((uint32_t)((const uint16_t*)cb)[(size_t)w * DIM + dd]);
    else         v = round_bf16(((const float*)cb)[(size_t)w * DIM + dd]);
    out[base + idx] = v;
  }

  // ---- per-block loss partial + last-block final reduction ----
  // Modulo counter: (old+1) % NBLOCKS == 0 fires exactly once per NBLOCKS
  // arrivals for ANY starting value -> no reset dispatch needed.
  if (tid == 0) {
    double s = 0.0;
    for (int i = 0; i < ROWS_PER_BLOCK; ++i) s += s_loss[i];
    partials[blockIdx.x] = s;
    __threadfence();                       // release partials (device scope)
    unsigned int old = atomicAdd(counter, 1u);
    s_last = (((old + 1u) % (unsigned int)NBLOCKS) == 0u) ? 1 : 0;
  }
  __syncthreads();
  if (s_last) {
    __threadfence();                       // acquire all partials
    if (tid < 128) s_loss[tid] = partials[tid] + partials[tid + 128];
    __syncthreads();
    if (tid == 0) {
      double t = 0.0;
      for (int i = 0; i < 128; ++i) t += s_loss[i];
      out[N_ELEMS] = round_bf16((float)(1.25 * t / (double)N_ELEMS));
    }
  }
}

extern "C" void kernel_launch(void* const* d_in, const int* in_sizes, int n_in,
                              void* d_out, int out_size, void* d_ws, size_t ws_size,
                              hipStream_t stream) {
  const void* z  = d_in[0];
  const void* cb = d_in[1];
  float* out = (float*)d_out;
  uint8_t* ws = (uint8_t*)d_ws;
  unsigned int* counter = (unsigned int*)(ws + 4096);
  double* partials = (double*)(ws + 8192);

  vq_kernel<<<NBLOCKS, THREADS, 0, stream>>>(z, cb, out, partials, counter);
}

// Round 19
// 133.131 us; speedup vs baseline: 1.2814x; 1.0068x over previous
//
#include <hip/hip_runtime.h>
#include <stdint.h>

// VectorQuantizer: z [32768,64], codebook [1024,64] (dtype sniffed bf16/f32).
// d_out FLOAT32: z_q_st [2097152] ++ loss [1] ++ indices [32768].
// Bit-exact replication of the reference f32 arithmetic (numpy pairwise sums,
// sequential non-fused dot, f32 final adds, first-index argmin).
//
// R22 = R21 (134.0us verified best) + ONE change on the bf16-codebook path:
// ct stored as PACKED bf16 pairs (u32 = codes {2j,2j+1} @ dim d) -> a
// thread's 8-code slice is 16B -> ONE ds_read_b128 per d instead of two.
// Per-d LDS reads 4 -> 3 (issue 98K -> 73.7K cyc/CU, -25%); +8 VALU unpack
// ops per d (+6%). Values bit-exact: stored bits ARE the input bf16 bits;
// bf_lo/bf_hi reproduce identical f32 operands; mul/add chain untouched.
// Staging pair-pack transpose: col = j ^ (w<<3) -> 64 distinct banks per
// store inst (2-way, free); read stays b128-contiguous (4 consecutive pairs
// share their 8-aligned group under the XOR). f32-cb fallback = R21 verbatim
// via type alias. Geometry/zt/merges/loss/modulo-counter: identical to R21.
#define N_ROWS 32768
#define DIM 64
#define K_CODES 1024
#define ROWS_PER_BLOCK 128
#define THREADS 512
#define CHUNK 256
#define NCHUNK (K_CODES / CHUNK)              // 4
#define NBLOCKS (N_ROWS / ROWS_PER_BLOCK)     // 256
#define N_ELEMS (N_ROWS * DIM)                // 2097152
#define ZT_STRIDE 128
#define CT_STRIDE 256

// workspace layout (bytes):
// [4096,4100)   uint counter (monotonic; modulo logic -> no reset required)
// [8192,10240)  double partials[NBLOCKS=256]

__device__ __forceinline__ float bfbits(uint32_t b) { return __uint_as_float(b << 16); }
__device__ __forceinline__ float bf_lo(uint32_t u) { return __uint_as_float(u << 16); }
__device__ __forceinline__ float bf_hi(uint32_t u) { return __uint_as_float(u & 0xFFFF0000u); }

// round f32 -> nearest bf16 value, returned AS f32 (RNE; finite inputs).
__device__ __forceinline__ float round_bf16(float f) {
  uint32_t u = __float_as_uint(f);
  uint32_t r = ((u + 0x7FFFu + ((u >> 16) & 1u)) >> 16) << 16;
  return __uint_as_float(r);
}

// zt split-plane column: row = 8*TR + s -> col = TR*4 + (s>>2)*64 + (s&3).
__device__ __forceinline__ int zcol(int row) {
  return ((row >> 3) << 2) + (((row >> 2) & 1) << 6) + (row & 3);
}

// numpy pairwise_sum for n=64 (8 accumulators, 8 rounds, numpy's combine tree).
template <typename F>
__device__ __forceinline__ float np_sum64(F get) {
  float r0 = get(0), r1 = get(1), r2 = get(2), r3 = get(3);
  float r4 = get(4), r5 = get(5), r6 = get(6), r7 = get(7);
  for (int i = 8; i < 64; i += 8) {
    r0 = __fadd_rn(r0, get(i + 0)); r1 = __fadd_rn(r1, get(i + 1));
    r2 = __fadd_rn(r2, get(i + 2)); r3 = __fadd_rn(r3, get(i + 3));
    r4 = __fadd_rn(r4, get(i + 4)); r5 = __fadd_rn(r5, get(i + 5));
    r6 = __fadd_rn(r6, get(i + 6)); r7 = __fadd_rn(r7, get(i + 7));
  }
  return __fadd_rn(__fadd_rn(__fadd_rn(r0, r1), __fadd_rn(r2, r3)),
                   __fadd_rn(__fadd_rn(r4, r5), __fadd_rn(r6, r7)));
}

// Thread tile: TR = tid&15 (8 rows), TK = tid>>4 in [0,32) (8 codes of 256).
__global__ __launch_bounds__(THREADS, 1) void vq_kernel(
    const void* __restrict__ z, const void* __restrict__ cb,
    float* __restrict__ out, double* __restrict__ partials,
    unsigned int* __restrict__ counter) {
  const int tid = threadIdx.x;

  __shared__ int s_cnt[2];
  __shared__ int s_last;
  __shared__ float zt[DIM][ZT_STRIDE];          // 32 KB, split-plane + XOR swz
  __shared__ uint32_t ctu[DIM][CT_STRIDE];      // 64 KB (bf16 path uses cols 0..127 as packed pairs)
  __shared__ float s_cc[K_CODES];               // 4 KB
  __shared__ float s_zz[ROWS_PER_BLOCK];        // 512 B
  __shared__ float s_bestW[8][ROWS_PER_BLOCK];  // 4 KB
  __shared__ int   s_kW[8][ROWS_PER_BLOCK];     // 4 KB
  __shared__ int   s_win[ROWS_PER_BLOCK];       // 512 B
  __shared__ double s_loss[ROWS_PER_BLOCK];     // 1 KB
  float (*ctf)[CT_STRIDE] = (float (*)[CT_STRIDE])ctu;  // f32-path alias

  // ---- per-block dtype sniff (identical logic/result in every block) ----
  if (tid < 2) s_cnt[tid] = 0;
  __syncthreads();
  if (tid < 128) {
    uint32_t wc = ((const uint32_t*)cb)[(size_t)tid * 255];
    float vc = fabsf(bfbits(wc & 0xFFFFu));
    if (vc == 0.0f || (vc > 5.9e-8f && vc < 32.0f)) atomicAdd(&s_cnt[1], 1);
    uint32_t wz = ((const uint32_t*)z)[(size_t)tid * 8191];
    float vz = fabsf(bfbits(wz & 0xFFFFu));
    if (vz == 0.0f || (vz > 5.9e-8f && vz < 32.0f)) atomicAdd(&s_cnt[0], 1);
  }
  __syncthreads();
  const bool z_bf16  = s_cnt[0] >= 96;
  const bool cb_bf16 = s_cnt[1] >= 96;

  const int TR = tid & 15;
  const int TK = tid >> 4;
  const size_t row0 = (size_t)blockIdx.x * ROWS_PER_BLOCK;

  // ---- s_cc from global: 2 codes/thread, 8-acc streaming numpy pairwise ----
  for (int kk = tid; kk < K_CODES; kk += THREADS) {
    float r0, r1, r2, r3, r4, r5, r6, r7;
    if (cb_bf16) {
      const uint4* cp = (const uint4*)((const uint16_t*)cb + (size_t)kk * DIM);
      uint4 u = cp[0];
      r0 = __fmul_rn(bf_lo(u.x), bf_lo(u.x)); r1 = __fmul_rn(bf_hi(u.x), bf_hi(u.x));
      r2 = __fmul_rn(bf_lo(u.y), bf_lo(u.y)); r3 = __fmul_rn(bf_hi(u.y), bf_hi(u.y));
      r4 = __fmul_rn(bf_lo(u.z), bf_lo(u.z)); r5 = __fmul_rn(bf_hi(u.z), bf_hi(u.z));
      r6 = __fmul_rn(bf_lo(u.w), bf_lo(u.w)); r7 = __fmul_rn(bf_hi(u.w), bf_hi(u.w));
      #pragma unroll
      for (int j = 1; j < 8; ++j) {
        u = cp[j];
        r0 = __fadd_rn(r0, __fmul_rn(bf_lo(u.x), bf_lo(u.x)));
        r1 = __fadd_rn(r1, __fmul_rn(bf_hi(u.x), bf_hi(u.x)));
        r2 = __fadd_rn(r2, __fmul_rn(bf_lo(u.y), bf_lo(u.y)));
        r3 = __fadd_rn(r3, __fmul_rn(bf_hi(u.y), bf_hi(u.y)));
        r4 = __fadd_rn(r4, __fmul_rn(bf_lo(u.z), bf_lo(u.z)));
        r5 = __fadd_rn(r5, __fmul_rn(bf_hi(u.z), bf_hi(u.z)));
        r6 = __fadd_rn(r6, __fmul_rn(bf_lo(u.w), bf_lo(u.w)));
        r7 = __fadd_rn(r7, __fmul_rn(bf_hi(u.w), bf_hi(u.w)));
      }
    } else {
      const float4* cp = (const float4*)((const float*)cb + (size_t)kk * DIM);
      float4 a = cp[0], b = cp[1];
      r0 = __fmul_rn(a.x, a.x); r1 = __fmul_rn(a.y, a.y);
      r2 = __fmul_rn(a.z, a.z); r3 = __fmul_rn(a.w, a.w);
      r4 = __fmul_rn(b.x, b.x); r5 = __fmul_rn(b.y, b.y);
      r6 = __fmul_rn(b.z, b.z); r7 = __fmul_rn(b.w, b.w);
      #pragma unroll
      for (int j = 1; j < 8; ++j) {
        a = cp[2 * j]; b = cp[2 * j + 1];
        r0 = __fadd_rn(r0, __fmul_rn(a.x, a.x));
        r1 = __fadd_rn(r1, __fmul_rn(a.y, a.y));
        r2 = __fadd_rn(r2, __fmul_rn(a.z, a.z));
        r3 = __fadd_rn(r3, __fmul_rn(a.w, a.w));
        r4 = __fadd_rn(r4, __fmul_rn(b.x, b.x));
        r5 = __fadd_rn(r5, __fmul_rn(b.y, b.y));
        r6 = __fadd_rn(r6, __fmul_rn(b.z, b.z));
        r7 = __fadd_rn(r7, __fmul_rn(b.w, b.w));
      }
    }
    s_cc[kk] = __fadd_rn(__fadd_rn(__fadd_rn(r0, r1), __fadd_rn(r2, r3)),
                         __fadd_rn(__fadd_rn(r4, r5), __fadd_rn(r6, r7)));
  }

  // ---- stage z transposed, split-plane + XOR swizzle (placement only) ----
  if (z_bf16) {
    const uint4* src = (const uint4*)((const uint16_t*)z + row0 * DIM);
    #pragma unroll
    for (int j = 0; j < 2; ++j) {
      int idx = tid + THREADS * j;              // [0,1024)
      int row = idx >> 3, w = idx & 7, d0 = w * 8;
      int col = zcol(row) ^ (w << 2);           // (d>>3)&7 == w for all 8 d's
      uint4 u = src[idx];
      zt[d0 + 0][col] = bf_lo(u.x); zt[d0 + 1][col] = bf_hi(u.x);
      zt[d0 + 2][col] = bf_lo(u.y); zt[d0 + 3][col] = bf_hi(u.y);
      zt[d0 + 4][col] = bf_lo(u.z); zt[d0 + 5][col] = bf_hi(u.z);
      zt[d0 + 6][col] = bf_lo(u.w); zt[d0 + 7][col] = bf_hi(u.w);
    }
  } else {
    const float4* src = (const float4*)((const float*)z + row0 * DIM);
    #pragma unroll
    for (int j = 0; j < 4; ++j) {
      int idx = tid + THREADS * j;              // [0,2048)
      int row = idx >> 4, d0 = (idx & 15) * 4;
      int col = zcol(row) ^ (((d0 >> 3) & 7) << 2);  // (d>>3) const over 4 d's
      float4 v = src[idx];
      zt[d0 + 0][col] = v.x; zt[d0 + 1][col] = v.y;
      zt[d0 + 2][col] = v.z; zt[d0 + 3][col] = v.w;
    }
  }
  __syncthreads();

  // zz per row = np.sum(z*z) in f32, numpy pairwise order over products.
  if (tid < ROWS_PER_BLOCK) {
    const int c0 = zcol(tid);
    s_zz[tid] = np_sum64([&](int d) {
      float v = zt[d][c0 ^ (((d >> 3) & 7) << 2)];
      return __fmul_rn(v, v); });
  }

  float best[8] = {3.4e38f, 3.4e38f, 3.4e38f, 3.4e38f,
                   3.4e38f, 3.4e38f, 3.4e38f, 3.4e38f};
  int bk[8] = {0, 0, 0, 0, 0, 0, 0, 0};
  float acc[8][8];
  #pragma unroll
  for (int ri = 0; ri < 8; ++ri)
    #pragma unroll
    for (int ki = 0; ki < 8; ++ki) acc[ri][ki] = 0.0f;

  if (cb_bf16) {
    // ======== bf16 path: packed-pair ct, 1 ds_read_b128 per d ========
    for (int c = 0; c < NCHUNK; ++c) {
      __syncthreads();  // prev chunk compute done (c=0: zz done)
      // stage: pair-pack transpose. task (j,w): codes {2j,2j+1}, dims 8w..8w+7.
      const uint4* src = (const uint4*)((const uint16_t*)cb + (size_t)c * CHUNK * DIM);
      #pragma unroll
      for (int t = 0; t < 2; ++t) {
        int task = tid + THREADS * t;           // [0,1024)
        int j = task >> 3, w = task & 7;
        uint4 a = src[(size_t)(2 * j) * 8 + w];       // code 2j,   dims 8w..
        uint4 b = src[(size_t)(2 * j + 1) * 8 + w];   // code 2j+1, dims 8w..
        int d0 = w * 8;
        int colb = j ^ (w << 3);                // 2-way banks on stores; read-contig
        ctu[d0 + 0][colb] = (a.x & 0xFFFFu) | (b.x << 16);
        ctu[d0 + 1][colb] = (a.x >> 16) | (b.x & 0xFFFF0000u);
        ctu[d0 + 2][colb] = (a.y & 0xFFFFu) | (b.y << 16);
        ctu[d0 + 3][colb] = (a.y >> 16) | (b.y & 0xFFFF0000u);
        ctu[d0 + 4][colb] = (a.z & 0xFFFFu) | (b.z << 16);
        ctu[d0 + 5][colb] = (a.z >> 16) | (b.z & 0xFFFF0000u);
        ctu[d0 + 6][colb] = (a.w & 0xFFFFu) | (b.w << 16);
        ctu[d0 + 7][colb] = (a.w >> 16) | (b.w & 0xFFFF0000u);
      }
      __syncthreads();

      // inner: per d, 3 ds_read_b128 (2 z + 1 packed c) feed 128 VALU ops +
      // 8 unpacks (non-fused; chain ascending d == reference einsum order).
      #pragma unroll 4
      for (int d = 0; d < DIM; ++d) {
        const int zs = ((d >> 3) & 7) << 2;
        const int X  = (d >> 3) << 3;
        float4 zA = *(const float4*)&zt[d][(TR << 2) ^ zs];        // rows 8TR+0..3
        float4 zB = *(const float4*)&zt[d][((TR << 2) ^ zs) + 64]; // rows 8TR+4..7
        uint4 cu = *(const uint4*)&ctu[d][(TK << 2) ^ X];          // 8 codes packed
        float zv[8] = {zA.x, zA.y, zA.z, zA.w, zB.x, zB.y, zB.z, zB.w};
        float cv[8] = {bf_lo(cu.x), bf_hi(cu.x), bf_lo(cu.y), bf_hi(cu.y),
                       bf_lo(cu.z), bf_hi(cu.z), bf_lo(cu.w), bf_hi(cu.w)};
        #pragma unroll
        for (int ri = 0; ri < 8; ++ri)
          #pragma unroll
          for (int ki = 0; ki < 8; ++ki)
            acc[ri][ki] = __fadd_rn(acc[ri][ki], __fmul_rn(zv[ri], cv[ki]));
      }

      // epilogue: d2 = fl(fl(zz+cc) - fl(2*g)); per-thread k ascending, strict <.
      #pragma unroll
      for (int ri = 0; ri < 8; ++ri) {
        const float zzr = s_zz[TR * 8 + ri];
        #pragma unroll
        for (int ki = 0; ki < 8; ++ki) {
          const int k = c * CHUNK + TK * 8 + ki;
          float e = __fsub_rn(__fadd_rn(zzr, s_cc[k]), __fmul_rn(2.0f, acc[ri][ki]));
          if (e < best[ri]) { best[ri] = e; bk[ri] = k; }
          acc[ri][ki] = 0.0f;
        }
      }
    }
  } else {
    // ======== f32 path: R21 verbatim via ctf alias ========
    for (int c = 0; c < NCHUNK; ++c) {
      __syncthreads();
      const float4* src = (const float4*)((const float*)cb + (size_t)c * CHUNK * DIM);
      #pragma unroll
      for (int j = 0; j < 8; ++j) {
        int idx = tid + THREADS * j;            // [0,4096)
        int kc = idx >> 4, d0 = (idx & 15) * 4;
        int col = kc ^ (((d0 >> 3) & 3) << 3);
        float4 v = src[idx];
        ctf[d0 + 0][col] = v.x; ctf[d0 + 1][col] = v.y;
        ctf[d0 + 2][col] = v.z; ctf[d0 + 3][col] = v.w;
      }
      __syncthreads();

      #pragma unroll 4
      for (int d = 0; d < DIM; ++d) {
        const int zs = ((d >> 3) & 7) << 2;
        const int cs = ((d >> 3) & 3) << 3;
        float4 zA = *(const float4*)&zt[d][(TR << 2) ^ zs];
        float4 zB = *(const float4*)&zt[d][((TR << 2) ^ zs) + 64];
        float4 cA = *(const float4*)&ctf[d][(TK << 3) ^ cs];
        float4 cB = *(const float4*)&ctf[d][((TK << 3) ^ cs) + 4];
        float zv[8] = {zA.x, zA.y, zA.z, zA.w, zB.x, zB.y, zB.z, zB.w};
        float cv[8] = {cA.x, cA.y, cA.z, cA.w, cB.x, cB.y, cB.z, cB.w};
        #pragma unroll
        for (int ri = 0; ri < 8; ++ri)
          #pragma unroll
          for (int ki = 0; ki < 8; ++ki)
            acc[ri][ki] = __fadd_rn(acc[ri][ki], __fmul_rn(zv[ri], cv[ki]));
      }

      #pragma unroll
      for (int ri = 0; ri < 8; ++ri) {
        const float zzr = s_zz[TR * 8 + ri];
        #pragma unroll
        for (int ki = 0; ki < 8; ++ki) {
          const int k = c * CHUNK + TK * 8 + ki;
          float e = __fsub_rn(__fadd_rn(zzr, s_cc[k]), __fmul_rn(2.0f, acc[ri][ki]));
          if (e < best[ri]) { best[ri] = e; bk[ri] = k; }
          acc[ri][ki] = 0.0f;
        }
      }
    }
  }

  // wave-level lexicographic merge across the 4 TK values in this wave.
  // Lex (d2,k) min is assoc/comm -> any merge order == first-index argmin.
  #pragma unroll
  for (int ri = 0; ri < 8; ++ri) {
    float v = best[ri]; int k = bk[ri];
    {
      float v2 = __shfl_xor(v, 16, 64); int k2 = __shfl_xor(k, 16, 64);
      if (v2 < v || (v2 == v && k2 < k)) { v = v2; k = k2; }
      v2 = __shfl_xor(v, 32, 64); k2 = __shfl_xor(k, 32, 64);
      if (v2 < v || (v2 == v && k2 < k)) { v = v2; k = k2; }
    }
    best[ri] = v; bk[ri] = k;
  }
  {
    const int lane = tid & 63, wv = tid >> 6;
    if (lane < 16) {
      #pragma unroll
      for (int ri = 0; ri < 8; ++ri) {
        s_bestW[wv][lane * 8 + ri] = best[ri];   // lane == TR here
        s_kW[wv][lane * 8 + ri] = bk[ri];
      }
    }
  }
  __syncthreads();

  if (tid < ROWS_PER_BLOCK) {
    // final lex merge across the 8 waves
    float b = 3.4e38f;
    int bbk = 0x7FFFFFFF;
    #pragma unroll
    for (int p = 0; p < 8; ++p) {
      float v = s_bestW[p][tid];
      int vk = s_kW[p][tid];
      if (v < b || (v == b && vk < bbk)) { b = v; bbk = vk; }
    }
    s_win[tid] = bbk;
    // Exact squared distance of the winner (fp64); exact z from zt column.
    const int c0 = zcol(tid);
    double acc2 = 0.0;
    if (cb_bf16) {
      const uint16_t* cp = (const uint16_t*)cb + (size_t)bbk * DIM;
      for (int d = 0; d < DIM; ++d) {
        double df = (double)zt[d][c0 ^ (((d >> 3) & 7) << 2)]
                  - (double)bfbits((uint32_t)cp[d]);
        acc2 = fma(df, df, acc2);
      }
    } else {
      const float* cp = (const float*)cb + (size_t)bbk * DIM;
      for (int d = 0; d < DIM; ++d) {
        double df = (double)zt[d][c0 ^ (((d >> 3) & 7) << 2)] - (double)cp[d];
        acc2 = fma(df, df, acc2);
      }
    }
    s_loss[tid] = acc2;
    out[(size_t)N_ELEMS + 1 + row0 + tid] = round_bf16((float)bbk);
  }
  __syncthreads();

  // z_q write: 128 rows x 64 dims = 8192 floats, 512 threads x 16, coalesced.
  const size_t base = row0 * DIM;
  #pragma unroll
  for (int j = 0; j < 16; ++j) {
    int idx = tid + THREADS * j;
    int rr = idx >> 6, dd = idx & 63;
    int w = s_win[rr];
    float v;
    if (cb_bf16) v = bfbits((uint32_t)((const uint16_t*)cb)[(size_t)w * DIM + dd]);
    else         v = round_bf16(((const float*)cb)[(size_t)w * DIM + dd]);
    out[base + idx] = v;
  }

  // ---- per-block loss partial + last-block final reduction ----
  // Modulo counter: (old+1) % NBLOCKS == 0 fires exactly once per NBLOCKS
  // arrivals for ANY starting value -> no reset dispatch needed.
  if (tid == 0) {
    double s = 0.0;
    for (int i = 0; i < ROWS_PER_BLOCK; ++i) s += s_loss[i];
    partials[blockIdx.x] = s;
    __threadfence();                       // release partials (device scope)
    unsigned int old = atomicAdd(counter, 1u);
    s_last = (((old + 1u) % (unsigned int)NBLOCKS) == 0u) ? 1 : 0;
  }
  __syncthreads();
  if (s_last) {
    __threadfence();                       // acquire all partials
    if (tid < 128) s_loss[tid] = partials[tid] + partials[tid + 128];
    __syncthreads();
    if (tid == 0) {
      double t = 0.0;
      for (int i = 0; i < 128; ++i) t += s_loss[i];
      out[N_ELEMS] = round_bf16((float)(1.25 * t / (double)N_ELEMS));
    }
  }
}

extern "C" void kernel_launch(void* const* d_in, const int* in_sizes, int n_in,
                              void* d_out, int out_size, void* d_ws, size_t ws_size,
                              hipStream_t stream) {
  const void* z  = d_in[0];
  const void* cb = d_in[1];
  float* out = (float*)d_out;
  uint8_t* ws = (uint8_t*)d_ws;
  unsigned int* counter = (unsigned int*)(ws + 4096);
  double* partials = (double*)(ws + 8192);

  vq_kernel<<<NBLOCKS, THREADS, 0, stream>>>(z, cb, out, partials, counter);
}